// Round 1
// 284.594 us; speedup vs baseline: 1.0925x; 1.0925x over previous
//
#include <hip/hip_runtime.h>
#include <hip/hip_bf16.h>

#define T_TOTAL 1000
#define B_TOTAL 128
#define F_TOTAL 2048
#define C_OUT   10
#define NEUR    (B_TOTAL * C_OUT)   // 1280

#define KSTEPS  (F_TOTAL / 32)      // 64 k-steps of 32
#define NBFRAG  (KSTEPS * 3 * 64)   // 12288 16-byte B fragments (hi/mid/lo)

typedef __attribute__((ext_vector_type(8))) short bf16x8;
typedef __attribute__((ext_vector_type(4))) float f32x4;

// ---------------------------------------------------------------------------
// Prep: split W exactly into three bf16 terms (W == hi+mid+lo in fp32) and
// store them frag-ordered: fragment idx = (s*3+p)*64 + lane, lane = 16g+r
// holds B[k = s*32 + 8g + j][col r], j=0..7 packed ascending.
// ---------------------------------------------------------------------------
__global__ __launch_bounds__(256) void snn_prep(const float* __restrict__ W,
                                                uint4* __restrict__ bfrag)
{
    const int idx = blockIdx.x * 256 + threadIdx.x;
    if (idx >= NBFRAG) return;
    const int l = idx & 63;
    const int sp = idx >> 6;
    const int p = sp % 3;            // split: 0=hi 1=mid 2=lo
    const int s = sp / 3;            // k-step
    const int g = l >> 4, r = l & 15;
    unsigned out[4] = {0u, 0u, 0u, 0u};
#pragma unroll
    for (int j = 0; j < 8; ++j) {
        const int k = s * 32 + g * 8 + j;
        const float wv = (r < C_OUT) ? W[k * C_OUT + r] : 0.f;
        __hip_bfloat16 bh = __float2bfloat16(wv);
        const float fh = __bfloat162float(bh);
        __hip_bfloat16 bm = __float2bfloat16(wv - fh);
        const float fm = __bfloat162float(bm);
        __hip_bfloat16 bl = __float2bfloat16(wv - fh - fm);   // exact residual
        __hip_bfloat16 sel = (p == 0) ? bh : (p == 1) ? bm : bl;
        const unsigned short bits = *reinterpret_cast<unsigned short*>(&sel);
        out[j >> 1] |= (unsigned)bits << (16 * (j & 1));
    }
    bfrag[idx] = make_uint4(out[0], out[1], out[2], out[3]);
}

// ---------------------------------------------------------------------------
// Phase 1 (MFMA): I[b*10+c][t] = x[b,t,:] @ W[:,c] via 3 exact bf16 splits.
// Block = 4 waves; each wave owns TWO 16-row t-tiles (32 rows) so every
// B-fragment load feeds 2 MFMAs (B request traffic halved vs 1-tile), and
// the k-loop is software-pipelined one step ahead with an explicit register
// ping-pong (no runtime-indexed arrays -> no scratch) so each wave always
// has the next step's 7 loads in flight while the current step's perms+MFMAs
// retire. Theory: previous version was latency-bound (~3.5 TB/s effective);
// this should push phase1 toward the ~6.3 TB/s read floor.
// ---------------------------------------------------------------------------
#define LOADS(S, A00, A01, A10, A11, B0, B1, B2)                              \
    A00 = *reinterpret_cast<const float4*>(arow0 + (S) * 32);                 \
    A01 = *reinterpret_cast<const float4*>(arow0 + (S) * 32 + 4);             \
    A10 = *reinterpret_cast<const float4*>(arow1 + (S) * 32);                 \
    A11 = *reinterpret_cast<const float4*>(arow1 + (S) * 32 + 4);             \
    B0  = bp[((S) * 3 + 0) * 64];                                             \
    B1  = bp[((S) * 3 + 1) * 64];                                             \
    B2  = bp[((S) * 3 + 2) * 64];

#define CONV(A0, A1, AF)                                                      \
    AF.u[0] = __builtin_amdgcn_perm(__float_as_uint(A0.y), __float_as_uint(A0.x), 0x07060302u); \
    AF.u[1] = __builtin_amdgcn_perm(__float_as_uint(A0.w), __float_as_uint(A0.z), 0x07060302u); \
    AF.u[2] = __builtin_amdgcn_perm(__float_as_uint(A1.y), __float_as_uint(A1.x), 0x07060302u); \
    AF.u[3] = __builtin_amdgcn_perm(__float_as_uint(A1.w), __float_as_uint(A1.z), 0x07060302u);

#define STEP(A00, A01, A10, A11, B0, B1, B2)                                  \
    {                                                                         \
        union { bf16x8 v; unsigned u[4]; } af0, af1;                          \
        CONV(A00, A01, af0)                                                   \
        CONV(A10, A11, af1)                                                   \
        union { bf16x8 v; uint4 q; } q0, q1, q2;                              \
        q0.q = B0; q1.q = B1; q2.q = B2;                                      \
        acc0 = __builtin_amdgcn_mfma_f32_16x16x32_bf16(af0.v, q0.v, acc0, 0, 0, 0); \
        acc1 = __builtin_amdgcn_mfma_f32_16x16x32_bf16(af1.v, q0.v, acc1, 0, 0, 0); \
        acc0 = __builtin_amdgcn_mfma_f32_16x16x32_bf16(af0.v, q1.v, acc0, 0, 0, 0); \
        acc1 = __builtin_amdgcn_mfma_f32_16x16x32_bf16(af1.v, q1.v, acc1, 0, 0, 0); \
        acc0 = __builtin_amdgcn_mfma_f32_16x16x32_bf16(af0.v, q2.v, acc0, 0, 0, 0); \
        acc1 = __builtin_amdgcn_mfma_f32_16x16x32_bf16(af1.v, q2.v, acc1, 0, 0, 0); \
    }

__global__ __launch_bounds__(256) void snn_phase1_mfma(
    const float* __restrict__ x, const uint4* __restrict__ bfrag,
    float* __restrict__ Ibuf, int t0, int cur)
{
    const int b  = blockIdx.y;
    const int w  = threadIdx.x >> 6;
    const int l  = threadIdx.x & 63;
    const int r  = l & 15, g = l >> 4;
    const int ttbase = blockIdx.x * 128 + w * 32;  // wave's 32-row tile (local t)

    // A-load rows for this lane: tile0 row = ttbase + (l&15), tile1 = +16,
    // k-octet = l>>4 (clamped dup rows for out-of-range t are discarded by
    // the store predicate).
    int t_row0 = t0 + ttbase + r;
    int t_row1 = t_row0 + 16;
    if (t_row0 > T_TOTAL - 1) t_row0 = T_TOTAL - 1;
    if (t_row1 > T_TOTAL - 1) t_row1 = T_TOTAL - 1;
    const float* __restrict__ arow0 =
        x + ((size_t)b * T_TOTAL + t_row0) * F_TOTAL + g * 8;
    const float* __restrict__ arow1 =
        x + ((size_t)b * T_TOTAL + t_row1) * F_TOTAL + g * 8;

    f32x4 acc0 = {0.f, 0.f, 0.f, 0.f};
    f32x4 acc1 = {0.f, 0.f, 0.f, 0.f};
    const uint4* __restrict__ bp = bfrag + l;

    float4 cA00, cA01, cA10, cA11; uint4 cB0, cB1, cB2;
    float4 nA00, nA01, nA10, nA11; uint4 nB0, nB1, nB2;

    LOADS(0, cA00, cA01, cA10, cA11, cB0, cB1, cB2)

#pragma unroll 1
    for (int s = 0; s < KSTEPS - 2; s += 2) {
        LOADS(s + 1, nA00, nA01, nA10, nA11, nB0, nB1, nB2)
        STEP(cA00, cA01, cA10, cA11, cB0, cB1, cB2)
        LOADS(s + 2, cA00, cA01, cA10, cA11, cB0, cB1, cB2)
        STEP(nA00, nA01, nA10, nA11, nB0, nB1, nB2)
    }
    LOADS(KSTEPS - 1, nA00, nA01, nA10, nA11, nB0, nB1, nB2)
    STEP(cA00, cA01, cA10, cA11, cB0, cB1, cB2)
    STEP(nA00, nA01, nA10, nA11, nB0, nB1, nB2)

    // C/D layout (m89): col = l&15, row = 4*(l>>4) + reg. Rows are t: the 4
    // regs are 4 consecutive t -> one float4 store per lane per tile.
    const int tt4_0 = ttbase + 4 * g;
    const int tt4_1 = tt4_0 + 16;
    if (r < C_OUT) {
        if (tt4_0 + 3 < cur) {
            const float4 v = make_float4(acc0[0], acc0[1], acc0[2], acc0[3]);
            *reinterpret_cast<float4*>(&Ibuf[((size_t)b * C_OUT + r) * cur + tt4_0]) = v;
        }
        if (tt4_1 + 3 < cur) {
            const float4 v = make_float4(acc1[0], acc1[1], acc1[2], acc1[3]);
            *reinterpret_cast<float4*>(&Ibuf[((size_t)b * C_OUT + r) * cur + tt4_1]) = v;
        }
    }
}

// ---------------------------------------------------------------------------
// Phase 2: per-neuron LIF scan, exact reference semantics (unchanged).
// ---------------------------------------------------------------------------
__device__ __forceinline__ void snn_step(float Iv, float& V, float& refr, float& cnt)
{
    const bool act = (refr <= 0.f);
    V += act ? Iv : 0.f;
    const bool fired = act && ((V - 0.4f) > 0.f);
    cnt += fired ? 1.f : 0.f;
    V    = fired ? 0.f : V;
    refr = fired ? 3.f : refr;
    refr = fmaxf(refr - 1.f, 0.f);
}

__global__ __launch_bounds__(256) void snn_phase2(
    const float* __restrict__ Ibuf, float* __restrict__ state,
    float* __restrict__ out, int t0, int Tc, int last)
{
    const int n = blockIdx.x * 256 + threadIdx.x;
    if (n >= NEUR) return;

    float V, refr, cnt;
    if (t0 == 0) { V = 0.f; refr = 0.f; cnt = 0.f; }
    else { V = state[n]; refr = state[NEUR + n]; cnt = state[2 * NEUR + n]; }

    const float* __restrict__ I = Ibuf + (size_t)n * Tc;

    int i = 0;
    for (; i + 16 <= Tc; i += 16) {
        const float4 a = *reinterpret_cast<const float4*>(I + i);
        const float4 b = *reinterpret_cast<const float4*>(I + i + 4);
        const float4 c = *reinterpret_cast<const float4*>(I + i + 8);
        const float4 d = *reinterpret_cast<const float4*>(I + i + 12);
        snn_step(a.x, V, refr, cnt); snn_step(a.y, V, refr, cnt);
        snn_step(a.z, V, refr, cnt); snn_step(a.w, V, refr, cnt);
        snn_step(b.x, V, refr, cnt); snn_step(b.y, V, refr, cnt);
        snn_step(b.z, V, refr, cnt); snn_step(b.w, V, refr, cnt);
        snn_step(c.x, V, refr, cnt); snn_step(c.y, V, refr, cnt);
        snn_step(c.z, V, refr, cnt); snn_step(c.w, V, refr, cnt);
        snn_step(d.x, V, refr, cnt); snn_step(d.y, V, refr, cnt);
        snn_step(d.z, V, refr, cnt); snn_step(d.w, V, refr, cnt);
    }
    for (; i < Tc; ++i) snn_step(I[i], V, refr, cnt);

    if (last) {
        out[n] = cnt;
    } else {
        state[n] = V; state[NEUR + n] = refr; state[2 * NEUR + n] = cnt;
    }
}

// ---------------------------------------------------------------------------
extern "C" void kernel_launch(void* const* d_in, const int* in_sizes, int n_in,
                              void* d_out, int out_size, void* d_ws, size_t ws_size,
                              hipStream_t stream)
{
    const float* x = (const float*)d_in[0];   // [128, 1000, 2048] fp32 {0,1}
    const float* W = (const float*)d_in[1];   // [2048, 10] fp32
    float* out = (float*)d_out;               // [128, 10] fp32

    // ws layout: state (15360 B) | bfrag (196608 B) | Ibuf
    float* state = (float*)d_ws;
    uint4* bfrag = (uint4*)((char*)d_ws + 3 * NEUR * sizeof(float));
    float* Ibuf  = (float*)((char*)d_ws + 3 * NEUR * sizeof(float) + NBFRAG * 16);

    snn_prep<<<(NBFRAG + 255) / 256, 256, 0, stream>>>(W, bfrag);

    // Chunk T so Ibuf fits the workspace (single chunk at ws ~4 GB).
    const size_t head = 3 * NEUR + NBFRAG * 4;          // floats consumed
    const size_t ws_floats = ws_size / sizeof(float);
    long avail = (long)ws_floats - (long)head;
    int Tc = (avail > 0) ? (int)(avail / NEUR) : 0;
    if (Tc > T_TOTAL) Tc = T_TOTAL;
    Tc &= ~3;
    if (Tc <= 0) Tc = 4;

    for (int t0 = 0; t0 < T_TOTAL; t0 += Tc) {
        int cur = T_TOTAL - t0; if (cur > Tc) cur = Tc;
        dim3 g1((cur + 127) / 128, B_TOTAL, 1);
        snn_phase1_mfma<<<g1, 256, 0, stream>>>(x, bfrag, Ibuf, t0, cur);
        const int last = (t0 + cur >= T_TOTAL) ? 1 : 0;
        snn_phase2<<<(NEUR + 255) / 256, 256, 0, stream>>>(Ibuf, state, out, t0, cur, last);
    }
}